// Round 1
// baseline (271.116 us; speedup 1.0000x reference)
//
#include <hip/hip_runtime.h>
#include <cstdint>

#define NROWS 16384
#define FDIM 64
#define HDIM 128
#define ODIM 512
#define KDIM 8192   // FDIM * HDIM

#define BM 128
#define BN 256
#define BK 64
#define NSTEPS (KDIM / BK)  // 128

typedef short bf16x8 __attribute__((ext_vector_type(8)));
typedef float f32x4 __attribute__((ext_vector_type(4)));
typedef uint32_t u32x4 __attribute__((ext_vector_type(4)));

__device__ __forceinline__ uint16_t rne_bf16(float f) {
  uint32_t u = __builtin_bit_cast(uint32_t, f);
  u += 0x7fffu + ((u >> 16) & 1u);
  return (uint16_t)(u >> 16);
}

// ---- pre-kernel 1: W2 [K=8192][O=512] f32 -> W2T [O][K] bf16 (LDS tile transpose) ----
__global__ void prep_w2t(const float* __restrict__ W2, uint16_t* __restrict__ W2T) {
  __shared__ float tile[64][65];
  const int k0 = blockIdx.x * 64;
  const int o0 = blockIdx.y * 64;
  const int tx = threadIdx.x;  // 0..63
  const int ty = threadIdx.y;  // 0..7
#pragma unroll
  for (int j = 0; j < 8; ++j)
    tile[ty + 8 * j][tx] = W2[(size_t)(k0 + ty + 8 * j) * ODIM + o0 + tx];
  __syncthreads();
#pragma unroll
  for (int j = 0; j < 8; ++j)
    W2T[(size_t)(o0 + ty + 8 * j) * KDIM + k0 + tx] = rne_bf16(tile[tx][ty + 8 * j]);
}

// ---- pre-kernel 2: b2sum[o] = sum_f b2[f][o] ----
__global__ void prep_b2sum(const float* __restrict__ b2, float* __restrict__ b2sum) {
  const int t = blockIdx.x * 256 + threadIdx.x;  // grid 2*256 = 512 = ODIM
  float s = 0.f;
#pragma unroll
  for (int f = 0; f < FDIM; ++f) s += b2[(size_t)f * ODIM + t];
  b2sum[t] = s;
}

// ---- main fused kernel: 128x256 tile, 8 waves (2m x 4n of 64x64), double-buffered
// LDS with prefetch-ahead: stage(t+1) issued BEFORE compute(t), single barrier/step.
// Four STATICALLY-NAMED LDS buffers (not As[2][...]) so alias analysis can prove
// stage-writes != compute-reads and the scheduler overlaps them.
__global__ __launch_bounds__(512, 2) void mlp_gemm(
    const float* __restrict__ x, const float* __restrict__ W1,
    const float* __restrict__ b1, const uint16_t* __restrict__ W2T,
    const float* __restrict__ b2sum, float* __restrict__ out) {
  __shared__ __align__(16) uint16_t As0[BM * BK];  // 16 KB each
  __shared__ __align__(16) uint16_t As1[BM * BK];
  __shared__ __align__(16) uint16_t Bs0[BN * BK];  // 32 KB each
  __shared__ __align__(16) uint16_t Bs1[BN * BK];

  const int tid = threadIdx.x;
  const int bid = blockIdx.x;
  // XCD pinning: blocks dispatch round-robin to 8 XCDs (bid&7). Give XCDs 0-3
  // o-half 0 and XCDs 4-7 o-half 1 -> each XCD's 4MB L2 holds exactly its 4MB
  // W2T slice. m-index covers 0..127 bijectively.
  const int g = bid & 7;
  const int o0 = (g >> 2) * BN;
  const int m0 = ((bid >> 3) * 4 + (g & 3)) * BM;

  const int wid = tid >> 6;   // 0..7
  const int lane = tid & 63;
  const int wm = wid >> 2;    // 0..1  wave m-slice (64 rows)
  const int wni = wid & 3;    // 0..3  wave n-slice (64 cols)
  const int q = lane >> 4;    // quad
  const int r = lane & 15;

  // A-staging roles: thread -> rows {ar, ar+64}, col-group ac (8 bf16 each)
  const int ar = tid >> 3;  // 0..63
  const int ac = tid & 7;   // 0..7
  // B-staging roles (global_load_lds: LDS = wave-uniform base + lane*16;
  // swizzle the GLOBAL col-group so fragment reads stay conflict-free)
  const int brow = lane >> 3;         // 0..7 within an 8-row chunk
  const int bcg = (lane & 7) ^ brow;  // swizzled col group

  const float* xp0 = x + (size_t)(m0 + ar) * FDIM;
  const float* xp1 = x + (size_t)(m0 + 64 + ar) * FDIM;
  const int aw0 = ar * BK + ((ac ^ (ar & 7)) * 8);         // (ar+64)&7 == ar&7
  const int aw1 = (ar + 64) * BK + ((ac ^ (ar & 7)) * 8);

  f32x4 acc[4][4];
#pragma unroll
  for (int i = 0; i < 4; ++i)
#pragma unroll
    for (int j = 0; j < 4; ++j) acc[i][j] = {0.f, 0.f, 0.f, 0.f};

  // stage step kk into (Ab, Bb): B via async global_load_lds, A via elu->ds_write
  auto stage = [&](uint16_t* Ab, uint16_t* Bb, int kk) {
#pragma unroll
    for (int j = 0; j < 4; ++j) {
      const int chunk = wid * 4 + j;  // 0..31, 1KB (8 rows x 64 cols) each
      const uint16_t* gp =
          W2T + (size_t)(o0 + chunk * 8 + brow) * KDIM + kk * BK + bcg * 8;
      uint16_t* lp = Bb + chunk * 512;  // wave-uniform base
      __builtin_amdgcn_global_load_lds(
          (const __attribute__((address_space(1))) uint32_t*)gp,
          (__attribute__((address_space(3))) uint32_t*)lp, 16, 0, 0);
    }
    const int f = kk >> 1;
    const int hoff = (kk & 1) * 64 + ac * 8;
    const float xv0 = xp0[f];
    const float xv1 = xp1[f];
    // W1/b1 read directly as f32 (drops the 16-op bf16 unpack; L1/L2 broadcast)
    float w1f[8], b1f[8];
    *(f32x4*)&w1f[0] = *(const f32x4*)(W1 + (size_t)f * HDIM + hoff);
    *(f32x4*)&w1f[4] = *(const f32x4*)(W1 + (size_t)f * HDIM + hoff + 4);
    *(f32x4*)&b1f[0] = *(const f32x4*)(b1 + (size_t)f * HDIM + hoff);
    *(f32x4*)&b1f[4] = *(const f32x4*)(b1 + (size_t)f * HDIM + hoff + 4);
    u32x4 ov0, ov1;
#pragma unroll
    for (int p = 0; p < 4; ++p) {
      float a0 = fmaf(xv0, w1f[2 * p], b1f[2 * p]);
      float a1 = fmaf(xv0, w1f[2 * p + 1], b1f[2 * p + 1]);
      float c0 = fmaf(xv1, w1f[2 * p], b1f[2 * p]);
      float c1 = fmaf(xv1, w1f[2 * p + 1], b1f[2 * p + 1]);
      // elu(p) = max(p, exp(min(p,0))-1): branch-free, no cndmask/vcc chain
      float e0 = fmaxf(a0, __expf(fminf(a0, 0.f)) - 1.f);
      float e1 = fmaxf(a1, __expf(fminf(a1, 0.f)) - 1.f);
      float g0 = fmaxf(c0, __expf(fminf(c0, 0.f)) - 1.f);
      float g1 = fmaxf(c1, __expf(fminf(c1, 0.f)) - 1.f);
      ov0[p] = __builtin_amdgcn_perm(__builtin_bit_cast(uint32_t, e1),
                                     __builtin_bit_cast(uint32_t, e0), 0x07060302u);
      ov1[p] = __builtin_amdgcn_perm(__builtin_bit_cast(uint32_t, g1),
                                     __builtin_bit_cast(uint32_t, g0), 0x07060302u);
    }
    *(u32x4*)(Ab + aw0) = ov0;
    *(u32x4*)(Ab + aw1) = ov1;
  };

  auto compute = [&](const uint16_t* Ab, const uint16_t* Bb) {
#pragma unroll
    for (int kc = 0; kc < 2; ++kc) {
      const int cg = kc * 4 + q;
      bf16x8 af[4], bfr[4];
#pragma unroll
      for (int mt = 0; mt < 4; ++mt) {
        const int row = wm * 64 + mt * 16 + r;
        af[mt] = *(const bf16x8*)&Ab[row * BK + ((cg ^ (row & 7)) * 8)];
      }
#pragma unroll
      for (int nt = 0; nt < 4; ++nt) {
        const int row = wni * 64 + nt * 16 + r;
        bfr[nt] = *(const bf16x8*)&Bb[row * BK + ((cg ^ (row & 7)) * 8)];
      }
#pragma unroll
      for (int mt = 0; mt < 4; ++mt)
#pragma unroll
        for (int nt = 0; nt < 4; ++nt)
          acc[mt][nt] = __builtin_amdgcn_mfma_f32_16x16x32_bf16(
              af[mt], bfr[nt], acc[mt][nt], 0, 0, 0);
    }
  };

  // prologue
  stage(As0, Bs0, 0);
  __syncthreads();

  // steady state: stage(t+1) issued before compute(t); loads drain at the
  // barrier, a full MFMA phase (~1200 cyc) after issue.
#pragma unroll 1
  for (int kk = 0; kk < NSTEPS - 2; kk += 2) {
    stage(As1, Bs1, kk + 1);
    compute(As0, Bs0);
    __syncthreads();
    stage(As0, Bs0, kk + 2);
    compute(As1, Bs1);
    __syncthreads();
  }
  // tail: steps 126 (in buf0) and 127
  stage(As1, Bs1, NSTEPS - 1);
  compute(As0, Bs0);
  __syncthreads();
  compute(As1, Bs1);

  // ---- epilogue: + sum_f b2, * 1/sqrt(F) ----
  float bsv[4];
#pragma unroll
  for (int nt = 0; nt < 4; ++nt) bsv[nt] = b2sum[o0 + wni * 64 + nt * 16 + r];
#pragma unroll
  for (int mt = 0; mt < 4; ++mt)
#pragma unroll
    for (int nt = 0; nt < 4; ++nt)
#pragma unroll
      for (int v = 0; v < 4; ++v) {
        const int row = m0 + wm * 64 + mt * 16 + q * 4 + v;  // C/D: row=(lane>>4)*4+reg
        const int col = o0 + wni * 64 + nt * 16 + r;         //      col=lane&15
        out[(size_t)row * ODIM + col] = (acc[mt][nt][v] + bsv[nt]) * 0.125f;
      }
}

extern "C" void kernel_launch(void* const* d_in, const int* in_sizes, int n_in,
                              void* d_out, int out_size, void* d_ws, size_t ws_size,
                              hipStream_t stream) {
  const float* x  = (const float*)d_in[0];
  const float* W1 = (const float*)d_in[1];
  const float* b1 = (const float*)d_in[2];
  const float* W2 = (const float*)d_in[3];
  const float* b2 = (const float*)d_in[4];
  float* out = (float*)d_out;

  char* ws = (char*)d_ws;
  float*    b2sum = (float*)ws;                     // 2KB
  uint16_t* W2T   = (uint16_t*)(ws + 65536);        // 8MB [O][K] bf16

  prep_w2t<<<dim3(KDIM / 64, ODIM / 64), dim3(64, 8), 0, stream>>>(W2, W2T);
  prep_b2sum<<<2, 256, 0, stream>>>(b2, b2sum);
  mlp_gemm<<<256, 512, 0, stream>>>(x, W1, b1, W2T, b2sum, out);
}